// Round 1
// baseline (136.928 us; speedup 1.0000x reference)
//
#include <hip/hip_runtime.h>

// out = 0.5 * sum_over_pooled( maxpool4( x @ W^T + b ) )  -> (batch,) fp32
// x: (M=4096, K=2048) f32, W: (N=4096, K=2048) f32, b: (N,) f32, out: (M,) f32
// Strategy: bf16 MFMA GEMM (16x16x32), fused bias+maxpool4+rowsum epilogue,
// atomicAdd into out (tolerance 11.44 >> atomic-order noise).

typedef float  f32x4   __attribute__((ext_vector_type(4)));
typedef short  bf16x8  __attribute__((ext_vector_type(8)));
typedef short  short4v __attribute__((ext_vector_type(4)));
typedef short  short8v __attribute__((ext_vector_type(8)));

__device__ __forceinline__ short f2bf(float f) {
    union { float f; unsigned u; } v; v.f = f;
    unsigned r = v.u + 0x7FFFu + ((v.u >> 16) & 1u);  // round-to-nearest-even
    return (short)(r >> 16);
}

// fp32 -> bf16 conversion of x and W into workspace (contiguous: [x_bf16][W_bf16])
__global__ void cvt_kernel(const float* __restrict__ x, const float* __restrict__ w,
                           short* __restrict__ out, long nx, long nw) {
    long total4 = (nx + nw) >> 2;
    long stride = (long)gridDim.x * blockDim.x;
    for (long i = (long)blockIdx.x * blockDim.x + threadIdx.x; i < total4; i += stride) {
        long e = i << 2;
        const float* src = (e < nx) ? (x + e) : (w + (e - nx));
        float4 v = *(const float4*)src;
        short4v s = { f2bf(v.x), f2bf(v.y), f2bf(v.z), f2bf(v.w) };
        *(short4v*)(out + e) = s;
    }
}

// 128x128 tile, BK=32, 256 threads = 4 waves (2x2), each wave 64x64 output.
// LDS layout matches MFMA fragment octets: [oct=k>>3][row][8 bf16] -> every
// ds_read_b128 is conflict-free (lanes 0..15 read 16 consecutive 16B blocks).
template<int SRC_BF16>
__global__ __launch_bounds__(256) void gemm_pool_kernel(
    const void* __restrict__ Ap, const void* __restrict__ Bp,
    const float* __restrict__ bias, float* __restrict__ out, int K)
{
    __shared__ short As[4][128][8];
    __shared__ short Bs[4][128][8];

    const int tid  = threadIdx.x;
    const int lane = tid & 63;
    const int wid  = tid >> 6;
    const int wr   = wid >> 1;     // wave row (0..1)
    const int wc   = wid & 1;      // wave col (0..1)
    const int hi   = lane >> 4;    // octet selector / row-quad selector
    const int lo   = lane & 15;
    const int brow = blockIdx.y * 128;
    const int bcol = blockIdx.x * 128;

    f32x4 acc[4][4] = {};

    const int nk = K >> 5;
    for (int kt = 0; kt < nk; ++kt) {
        if (kt) __syncthreads();          // previous iter's readers done
        const int kbase = kt * 32;

        if (SRC_BF16) {
            const short* A = (const short*)Ap;
            const short* B = (const short*)Bp;
#pragma unroll
            for (int it = 0; it < 2; ++it) {
                int item = it * 256 + tid;
                int oct = item & 3, row = item >> 2;
                const short* ga = A + (size_t)(brow + row) * K + kbase + oct * 8;
                const short* gb = B + (size_t)(bcol + row) * K + kbase + oct * 8;
                short8v sa = *(const short8v*)ga;
                short8v sb = *(const short8v*)gb;
                *(short8v*)&As[oct][row][0] = sa;
                *(short8v*)&Bs[oct][row][0] = sb;
            }
        } else {
            const float* A = (const float*)Ap;
            const float* B = (const float*)Bp;
#pragma unroll
            for (int it = 0; it < 2; ++it) {
                int item = it * 256 + tid;
                int c = item & 3, row = item >> 2;   // c: which 4-float chunk
                {
                    const float* g = A + (size_t)(brow + row) * K + kbase + c * 4;
                    float4 v0 = *(const float4*)g;
                    float4 v1 = *(const float4*)(g + 16);
                    short4v s0 = { f2bf(v0.x), f2bf(v0.y), f2bf(v0.z), f2bf(v0.w) };
                    short4v s1 = { f2bf(v1.x), f2bf(v1.y), f2bf(v1.z), f2bf(v1.w) };
                    *(short4v*)&As[c >> 1][row][(c & 1) * 4]     = s0;
                    *(short4v*)&As[2 + (c >> 1)][row][(c & 1) * 4] = s1;
                }
                {
                    const float* g = B + (size_t)(bcol + row) * K + kbase + c * 4;
                    float4 v0 = *(const float4*)g;
                    float4 v1 = *(const float4*)(g + 16);
                    short4v s0 = { f2bf(v0.x), f2bf(v0.y), f2bf(v0.z), f2bf(v0.w) };
                    short4v s1 = { f2bf(v1.x), f2bf(v1.y), f2bf(v1.z), f2bf(v1.w) };
                    *(short4v*)&Bs[c >> 1][row][(c & 1) * 4]     = s0;
                    *(short4v*)&Bs[2 + (c >> 1)][row][(c & 1) * 4] = s1;
                }
            }
        }
        __syncthreads();

        bf16x8 af[4], bf[4];
#pragma unroll
        for (int m = 0; m < 4; ++m)
            af[m] = *(const bf16x8*)&As[hi][wr * 64 + m * 16 + lo][0];
#pragma unroll
        for (int n = 0; n < 4; ++n)
            bf[n] = *(const bf16x8*)&Bs[hi][wc * 64 + n * 16 + lo][0];
#pragma unroll
        for (int m = 0; m < 4; ++m)
#pragma unroll
            for (int n = 0; n < 4; ++n)
                acc[m][n] = __builtin_amdgcn_mfma_f32_16x16x32_bf16(
                    af[m], bf[n], acc[m][n], 0, 0, 0);
    }

    // Epilogue: bias + maxpool4(cols) + rowsum, fused.
    // C/D frag mapping: col = lane&15, row = (lane>>4)*4 + reg  [m89-verified]
    float bias_n[4];
#pragma unroll
    for (int n = 0; n < 4; ++n)
        bias_n[n] = bias[bcol + wc * 64 + n * 16 + lo];

#pragma unroll
    for (int m = 0; m < 4; ++m) {
#pragma unroll
        for (int j = 0; j < 4; ++j) {
            float part = 0.f;
#pragma unroll
            for (int n = 0; n < 4; ++n) {
                float v = acc[m][n][j] + bias_n[n];
                v = fmaxf(v, __shfl_xor(v, 1));   // pool across col bit 0
                v = fmaxf(v, __shfl_xor(v, 2));   // pool across col bit 1
                part += v;                        // lane holds pooled[(lo>>2)]
            }
            part += __shfl_xor(part, 4);          // sum the 4 pool groups
            part += __shfl_xor(part, 8);          // (exact, no replication)
            if (lo == 0)
                atomicAdd(&out[brow + wr * 64 + m * 16 + hi * 4 + j], part * 0.5f);
        }
    }
}

extern "C" void kernel_launch(void* const* d_in, const int* in_sizes, int n_in,
                              void* d_out, int out_size, void* d_ws, size_t ws_size,
                              hipStream_t stream) {
    const float* x = (const float*)d_in[0];
    const float* W = (const float*)d_in[1];
    const float* b = (const float*)d_in[2];
    float* out = (float*)d_out;

    const int N = in_sizes[2];             // out_f = 4096
    const int K = in_sizes[1] / N;         // in_f  = 2048
    const int M = in_sizes[0] / K;         // batch = 4096

    // Atomics accumulate into out -> must zero every call (graph replays).
    hipMemsetAsync(out, 0, (size_t)out_size * sizeof(float), stream);

    dim3 grid(N / 128, M / 128);
    const size_t need = ((size_t)in_sizes[0] + (size_t)in_sizes[1]) * sizeof(short);

    if (ws_size >= need) {
        short* xb = (short*)d_ws;
        short* wb = xb + in_sizes[0];
        cvt_kernel<<<2048, 256, 0, stream>>>(x, W, (short*)d_ws,
                                             (long)in_sizes[0], (long)in_sizes[1]);
        gemm_pool_kernel<1><<<grid, 256, 0, stream>>>(xb, wb, b, out, K);
    } else {
        gemm_pool_kernel<0><<<grid, 256, 0, stream>>>(x, W, b, out, K);
    }
}

// Round 2
// 130.766 us; speedup vs baseline: 1.0471x; 1.0471x over previous
//
#include <hip/hip_runtime.h>

// out = 0.5 * sum_over_pooled( maxpool4( x @ W^T + b ) )  -> (batch,) fp32
// x: (M=4096, K=2048) f32, W: (N=4096, K=2048) f32, b: (N,) f32, out: (M,) f32
// Strategy: cvt to bf16 in ws, then 128x128 MFMA GEMM with global_load_lds
// (width=16) staging + pre-swizzled source, fused bias+maxpool4+rowsum epilogue.

typedef float  f32x4   __attribute__((ext_vector_type(4)));
typedef short  bf16x8  __attribute__((ext_vector_type(8)));
typedef short  short4v __attribute__((ext_vector_type(4)));

__device__ __forceinline__ short f2bf(float f) {
    union { float f; unsigned u; } v; v.f = f;
    unsigned r = v.u + 0x7FFFu + ((v.u >> 16) & 1u);  // round-to-nearest-even
    return (short)(r >> 16);
}

// fp32 -> bf16 conversion of x and W into workspace (contiguous: [x_bf16][W_bf16])
__global__ void cvt_kernel(const float* __restrict__ x, const float* __restrict__ w,
                           short* __restrict__ out, long nx, long nw) {
    long total4 = (nx + nw) >> 2;
    long stride = (long)gridDim.x * blockDim.x;
    for (long i = (long)blockIdx.x * blockDim.x + threadIdx.x; i < total4; i += stride) {
        long e = i << 2;
        const float* src = (e < nx) ? (x + e) : (w + (e - nx));
        float4 v = *(const float4*)src;
        short4v s = { f2bf(v.x), f2bf(v.y), f2bf(v.z), f2bf(v.w) };
        *(short4v*)(out + e) = s;
    }
}

// 128x128 tile, BK=32, 256 threads = 4 waves (2x2), each wave 64x64 output.
// LDS logical layout: A-row r (64B = 4 x 16B k-octets), octet q stored at
// slot q^(r&3)  -> swizzled ds_read_b128 is bank-conflict-free, and the
// as-loaded order is LINEAR so global_load_lds can write it directly with a
// pre-swizzled per-lane GLOBAL source octet (l&3)^((l>>2)&3).
__global__ __launch_bounds__(256) void gemm_pool_kernel(
    const short* __restrict__ A, const short* __restrict__ B,
    const float* __restrict__ bias, float* __restrict__ out, int K)
{
    __shared__ short As[4096];   // 8 KB: 128 rows x 32 k-elems (swizzled slots)
    __shared__ short Bs[4096];

    const int tid  = threadIdx.x;
    const int lane = tid & 63;
    const int wid  = tid >> 6;
    const int wr   = wid >> 1;     // wave row (0..1)
    const int wc   = wid & 1;      // wave col (0..1)
    const int hi   = lane >> 4;    // k-octet selector for MFMA frags
    const int lo   = lane & 15;
    const int brow = blockIdx.y * 128;
    const int bcol = blockIdx.x * 128;

    // staging geometry: wave chunk c covers rows c*16..c*16+15 (1024B linear)
    const int srow  = lane >> 2;                 // 0..15 within chunk
    const int skoct = (lane & 3) ^ (srow & 3);   // pre-swizzled source octet

    f32x4 acc[4][4] = {};

    const int nk = K >> 5;
    for (int kt = 0; kt < nk; ++kt) {
        if (kt) __syncthreads();          // previous iter's readers done
        const int kbase = kt * 32;

#pragma unroll
        for (int i = 0; i < 2; ++i) {
            const int c   = wid * 2 + i;          // chunk 0..7
            const int row = c * 16 + srow;
            const short* ga = A + (size_t)(brow + row) * K + kbase + skoct * 8;
            const short* gb = B + (size_t)(bcol + row) * K + kbase + skoct * 8;
            __builtin_amdgcn_global_load_lds(
                (const __attribute__((address_space(1))) unsigned int*)ga,
                (__attribute__((address_space(3))) unsigned int*)&As[c * 512],
                16, 0, 0);
            __builtin_amdgcn_global_load_lds(
                (const __attribute__((address_space(1))) unsigned int*)gb,
                (__attribute__((address_space(3))) unsigned int*)&Bs[c * 512],
                16, 0, 0);
        }
        __syncthreads();                  // drains vmcnt(0) + barrier

        bf16x8 af[4], bf[4];
        const int slot = (hi ^ (lo & 3)) << 3;    // short offset of 16B slot
#pragma unroll
        for (int m = 0; m < 4; ++m) {
            const int r = wr * 64 + m * 16 + lo;
            af[m] = *(const bf16x8*)&As[r * 32 + slot];
        }
#pragma unroll
        for (int n = 0; n < 4; ++n) {
            const int r = wc * 64 + n * 16 + lo;
            bf[n] = *(const bf16x8*)&Bs[r * 32 + slot];
        }
#pragma unroll
        for (int m = 0; m < 4; ++m)
#pragma unroll
            for (int n = 0; n < 4; ++n)
                acc[m][n] = __builtin_amdgcn_mfma_f32_16x16x32_bf16(
                    af[m], bf[n], acc[m][n], 0, 0, 0);
    }

    // Epilogue: bias + maxpool4(cols) + rowsum, fused.
    // C/D frag mapping: col = lane&15, row = (lane>>4)*4 + reg  [m89-verified]
    float bias_n[4];
#pragma unroll
    for (int n = 0; n < 4; ++n)
        bias_n[n] = bias[bcol + wc * 64 + n * 16 + lo];

#pragma unroll
    for (int m = 0; m < 4; ++m) {
#pragma unroll
        for (int j = 0; j < 4; ++j) {
            float part = 0.f;
#pragma unroll
            for (int n = 0; n < 4; ++n) {
                float v = acc[m][n][j] + bias_n[n];
                v = fmaxf(v, __shfl_xor(v, 1));   // pool across col bit 0
                v = fmaxf(v, __shfl_xor(v, 2));   // pool across col bit 1
                part += v;                        // lane holds pooled[(lo>>2)]
            }
            part += __shfl_xor(part, 4);          // sum the 4 pool groups
            part += __shfl_xor(part, 8);          // (exact, no replication)
            if (lo == 0)
                atomicAdd(&out[brow + wr * 64 + m * 16 + hi * 4 + j], part * 0.5f);
        }
    }
}

extern "C" void kernel_launch(void* const* d_in, const int* in_sizes, int n_in,
                              void* d_out, int out_size, void* d_ws, size_t ws_size,
                              hipStream_t stream) {
    const float* x = (const float*)d_in[0];
    const float* W = (const float*)d_in[1];
    const float* b = (const float*)d_in[2];
    float* out = (float*)d_out;

    const int N = in_sizes[2];             // out_f = 4096
    const int K = in_sizes[1] / N;         // in_f  = 2048
    const int M = in_sizes[0] / K;         // batch = 4096

    // Atomics accumulate into out -> must zero every call (graph replays).
    hipMemsetAsync(out, 0, (size_t)out_size * sizeof(float), stream);

    short* xb = (short*)d_ws;
    short* wb = xb + in_sizes[0];
    cvt_kernel<<<2048, 256, 0, stream>>>(x, W, (short*)d_ws,
                                         (long)in_sizes[0], (long)in_sizes[1]);

    dim3 grid(N / 128, M / 128);
    gemm_pool_kernel<<<grid, 256, 0, stream>>>(xb, wb, b, out, K);
}

// Round 3
// 92.540 us; speedup vs baseline: 1.4797x; 1.4131x over previous
//
#include <hip/hip_runtime.h>

// out = 0.5 * sum_over_pooled( maxpool4( x @ W^T + b ) )  -> (batch,) fp32
// x: (M=4096, K=2048) f32, W: (N=4096, K=2048) f32, b: (N,) f32, out: (M,) f32
// Strategy: cvt to bf16 in ws, then 256x256 8-phase pipelined MFMA GEMM
// (T2 conflict-free swizzle + T3/T4 counted-vmcnt schedule + T5 setprio),
// fused bias+maxpool4+rowsum epilogue with atomicAdd.

typedef float  f32x4   __attribute__((ext_vector_type(4)));
typedef short  bf16x8  __attribute__((ext_vector_type(8)));
typedef short  short4v __attribute__((ext_vector_type(4)));

__device__ __forceinline__ short f2bf(float f) {
    union { float f; unsigned u; } v; v.f = f;
    unsigned r = v.u + 0x7FFFu + ((v.u >> 16) & 1u);  // round-to-nearest-even
    return (short)(r >> 16);
}

__global__ void cvt_kernel(const float* __restrict__ x, const float* __restrict__ w,
                           short* __restrict__ out, long nx, long nw) {
    long total4 = (nx + nw) >> 2;
    long stride = (long)gridDim.x * blockDim.x;
    for (long i = (long)blockIdx.x * blockDim.x + threadIdx.x; i < total4; i += stride) {
        long e = i << 2;
        const float* src = (e < nx) ? (x + e) : (w + (e - nx));
        float4 v = *(const float4*)src;
        short4v s = { f2bf(v.x), f2bf(v.y), f2bf(v.z), f2bf(v.w) };
        *(short4v*)(out + e) = s;
    }
}

// ---------------- 256x256 8-phase GEMM + fused pool ----------------
// LDS layout per 32KB tile buffer: chunk c = rows [8c..8c+7]; within chunk:
// (row&7)*128B + slot*16B where slot = q ^ (row&7), q = k-16B-index (0..7).
// -> each aligned 8-lane group of a ds_read_b128 covers all 8 bank-quads
//    exactly once (zero conflicts); staging source is 128B-contiguous per
//    8 lanes (perfect coalescing), LDS dest linear for global_load_lds.
#define LDSOFF(rc, q) ((((rc) >> 3) << 9) + (((rc) & 7) << 6) + ((((q) ^ ((rc) & 7))) << 3))

__device__ __forceinline__ void stage_A(const short* __restrict__ G, short* lds,
                                        int blockRow, int K, int kt, int half,
                                        int wid, int lane) {
    // half 0: chunks {0..7,16..23} (rows 0-63,128-191); half 1: {8..15,24..31}
#pragma unroll
    for (int i = 0; i < 2; ++i) {
        int idx = wid * 2 + i;                                // 0..15
        int c   = (idx & 7) + ((idx >> 3) << 4) + (half << 3);
        int row = (c << 3) + (lane >> 3);
        int q   = (lane & 7) ^ (lane >> 3);                   // pre-swizzled src slot
        const short* src = G + (size_t)(blockRow + row) * K + kt * 64 + q * 8;
        __builtin_amdgcn_global_load_lds(
            (const __attribute__((address_space(1))) unsigned int*)src,
            (__attribute__((address_space(3))) unsigned int*)(lds + c * 512),
            16, 0, 0);
    }
}

__device__ __forceinline__ void stage_B(const short* __restrict__ G, short* lds,
                                        int blockCol, int K, int kt, int half,
                                        int wid, int lane) {
    // half 0: chunks {0-3,8-11,16-19,24-27} (cols 0-31,64-95,...); half 1: +4
#pragma unroll
    for (int i = 0; i < 2; ++i) {
        int idx = wid * 2 + i;
        int c   = ((idx >> 2) << 3) + (idx & 3) + (half << 2);
        int row = (c << 3) + (lane >> 3);
        int q   = (lane & 7) ^ (lane >> 3);
        const short* src = G + (size_t)(blockCol + row) * K + kt * 64 + q * 8;
        __builtin_amdgcn_global_load_lds(
            (const __attribute__((address_space(1))) unsigned int*)src,
            (__attribute__((address_space(3))) unsigned int*)(lds + c * 512),
            16, 0, 0);
    }
}

__global__ __launch_bounds__(512, 2) void gemm_pool_kernel(
    const short* __restrict__ X, const short* __restrict__ W,
    const float* __restrict__ bias, float* __restrict__ out, int K)
{
    __shared__ short As[32768];   // 64 KB: 2 x (256 rows x 64 k)
    __shared__ short Bs[32768];   // 64 KB

    const int tid  = threadIdx.x;
    const int lane = tid & 63;
    const int wid  = tid >> 6;     // 0..7
    const int wr   = wid >> 2;     // 0..1  (wave row: 128 rows each)
    const int wc   = wid & 3;      // 0..3  (wave col: 64 cols each)
    const int hi   = lane >> 4;
    const int lo   = lane & 15;
    const int brow = blockIdx.y * 256;
    const int bcol = blockIdx.x * 256;
    const int nk   = K >> 6;       // 64-wide K tiles (assumes nk >= 3)

    f32x4 acc[8][4] = {};
    bf16x8 a[4][2], bq[2][2];

    // Prologue: stage T0 fully + T1 minus its B-q0 (staged at t=0 P1).
    stage_A(X, As,         brow, K, 0, 0, wid, lane);
    stage_B(W, Bs,         bcol, K, 0, 0, wid, lane);
    stage_B(W, Bs,         bcol, K, 0, 1, wid, lane);
    stage_A(X, As,         brow, K, 0, 1, wid, lane);
    stage_A(X, As + 16384, brow, K, 1, 0, wid, lane);
    stage_B(W, Bs + 16384, bcol, K, 1, 1, wid, lane);
    stage_A(X, As + 16384, brow, K, 1, 1, wid, lane);
    asm volatile("s_waitcnt vmcnt(6)" ::: "memory");  // T0 complete; last 3 halves in flight
    __builtin_amdgcn_s_barrier();

    for (int t = 0; t < nk; ++t) {
        short* Ab = As + ((t & 1) << 14);
        short* Bb = Bs + ((t & 1) << 14);
        short* Bn = Bs + (((t & 1) ^ 1) << 14);

        // ---- P1: quad (m-half 0, n-half 0); stage B-q0(t+1) -> other buf
#pragma unroll
        for (int mm = 0; mm < 4; ++mm)
#pragma unroll
            for (int kk = 0; kk < 2; ++kk) {
                int rc = wr * 128 + mm * 16 + lo;
                a[mm][kk] = *(const bf16x8*)(Ab + LDSOFF(rc, kk * 4 + hi));
            }
#pragma unroll
        for (int nn = 0; nn < 2; ++nn)
#pragma unroll
            for (int kk = 0; kk < 2; ++kk) {
                int rc = wc * 64 + nn * 16 + lo;
                bq[nn][kk] = *(const bf16x8*)(Bb + LDSOFF(rc, kk * 4 + hi));
            }
        if (t + 1 < nk) stage_B(W, Bn, bcol, K, t + 1, 0, wid, lane);
        __builtin_amdgcn_s_barrier();
        __builtin_amdgcn_s_setprio(1);
#pragma unroll
        for (int mm = 0; mm < 4; ++mm)
#pragma unroll
            for (int nn = 0; nn < 2; ++nn)
#pragma unroll
                for (int kk = 0; kk < 2; ++kk)
                    acc[mm][nn] = __builtin_amdgcn_mfma_f32_16x16x32_bf16(
                        a[mm][kk], bq[nn][kk], acc[mm][nn], 0, 0, 0);
        __builtin_amdgcn_s_setprio(0);
        __builtin_amdgcn_s_barrier();

        // ---- P2: quad (0,1); stage A-q0(t+2) -> same buf (A-q0 free after P1)
#pragma unroll
        for (int nn = 0; nn < 2; ++nn)
#pragma unroll
            for (int kk = 0; kk < 2; ++kk) {
                int rc = wc * 64 + 32 + nn * 16 + lo;
                bq[nn][kk] = *(const bf16x8*)(Bb + LDSOFF(rc, kk * 4 + hi));
            }
        if (t + 2 < nk) stage_A(X, Ab, brow, K, t + 2, 0, wid, lane);
        __builtin_amdgcn_s_barrier();
        __builtin_amdgcn_s_setprio(1);
#pragma unroll
        for (int mm = 0; mm < 4; ++mm)
#pragma unroll
            for (int nn = 0; nn < 2; ++nn)
#pragma unroll
                for (int kk = 0; kk < 2; ++kk)
                    acc[mm][2 + nn] = __builtin_amdgcn_mfma_f32_16x16x32_bf16(
                        a[mm][kk], bq[nn][kk], acc[mm][2 + nn], 0, 0, 0);
        __builtin_amdgcn_s_setprio(0);
        __builtin_amdgcn_s_barrier();

        // ---- P3: quad (1,1); stage B-q1(t+2) (B-q1 free after P2); reuse bq
#pragma unroll
        for (int mm = 0; mm < 4; ++mm)
#pragma unroll
            for (int kk = 0; kk < 2; ++kk) {
                int rc = wr * 128 + 64 + mm * 16 + lo;
                a[mm][kk] = *(const bf16x8*)(Ab + LDSOFF(rc, kk * 4 + hi));
            }
        if (t + 2 < nk) stage_B(W, Bb, bcol, K, t + 2, 1, wid, lane);
        __builtin_amdgcn_s_barrier();
        __builtin_amdgcn_s_setprio(1);
#pragma unroll
        for (int mm = 0; mm < 4; ++mm)
#pragma unroll
            for (int nn = 0; nn < 2; ++nn)
#pragma unroll
                for (int kk = 0; kk < 2; ++kk)
                    acc[4 + mm][2 + nn] = __builtin_amdgcn_mfma_f32_16x16x32_bf16(
                        a[mm][kk], bq[nn][kk], acc[4 + mm][2 + nn], 0, 0, 0);
        __builtin_amdgcn_s_setprio(0);
        __builtin_amdgcn_s_barrier();

        // ---- P4: quad (1,0); stage A-q1(t+2) (A-q1 free after P3)
#pragma unroll
        for (int nn = 0; nn < 2; ++nn)
#pragma unroll
            for (int kk = 0; kk < 2; ++kk) {
                int rc = wc * 64 + nn * 16 + lo;
                bq[nn][kk] = *(const bf16x8*)(Bb + LDSOFF(rc, kk * 4 + hi));
            }
        if (t + 2 < nk) stage_A(X, Ab, brow, K, t + 2, 1, wid, lane);
        __builtin_amdgcn_s_barrier();
        __builtin_amdgcn_s_setprio(1);
#pragma unroll
        for (int mm = 0; mm < 4; ++mm)
#pragma unroll
            for (int nn = 0; nn < 2; ++nn)
#pragma unroll
                for (int kk = 0; kk < 2; ++kk)
                    acc[4 + mm][nn] = __builtin_amdgcn_mfma_f32_16x16x32_bf16(
                        a[mm][kk], bq[nn][kk], acc[4 + mm][nn], 0, 0, 0);
        __builtin_amdgcn_s_setprio(0);
        // Tile-boundary wait BEFORE the barrier => proper cross-wave
        // happens-before: every wave's relevant staging retired before any
        // wave reads the next tile. Steady state keeps newest 3 half-tiles
        // (6 loads) in flight; drain fully before the last tile.
        if (t == nk - 2)      asm volatile("s_waitcnt vmcnt(0)" ::: "memory");
        else if (t < nk - 2)  asm volatile("s_waitcnt vmcnt(6)" ::: "memory");
        __builtin_amdgcn_s_barrier();
    }

    // Epilogue: bias + maxpool4(cols) + rowsum, fused.
    // C/D frag mapping: col = lane&15, row = (lane>>4)*4 + reg  [m89-verified]
    float bias_n[4];
#pragma unroll
    for (int nn = 0; nn < 4; ++nn)
        bias_n[nn] = bias[bcol + wc * 64 + nn * 16 + lo];

#pragma unroll
    for (int mm = 0; mm < 8; ++mm) {
#pragma unroll
        for (int j = 0; j < 4; ++j) {
            float part = 0.f;
#pragma unroll
            for (int nn = 0; nn < 4; ++nn) {
                float v = acc[mm][nn][j] + bias_n[nn];
                v = fmaxf(v, __shfl_xor(v, 1));   // pool across col bit 0
                v = fmaxf(v, __shfl_xor(v, 2));   // pool across col bit 1
                part += v;                        // lane holds pooled[(lo>>2)]
            }
            part += __shfl_xor(part, 4);          // sum the 4 pool groups
            part += __shfl_xor(part, 8);
            if (lo == 0)
                atomicAdd(&out[brow + wr * 128 + mm * 16 + hi * 4 + j], part * 0.5f);
        }
    }
}

extern "C" void kernel_launch(void* const* d_in, const int* in_sizes, int n_in,
                              void* d_out, int out_size, void* d_ws, size_t ws_size,
                              hipStream_t stream) {
    const float* x = (const float*)d_in[0];
    const float* W = (const float*)d_in[1];
    const float* b = (const float*)d_in[2];
    float* out = (float*)d_out;

    const int N = in_sizes[2];             // out_f = 4096
    const int K = in_sizes[1] / N;         // in_f  = 2048
    const int M = in_sizes[0] / K;         // batch = 4096

    // Atomics accumulate into out -> must zero every call (graph replays).
    hipMemsetAsync(out, 0, (size_t)out_size * sizeof(float), stream);

    short* xb = (short*)d_ws;
    short* wb = xb + in_sizes[0];
    cvt_kernel<<<2048, 256, 0, stream>>>(x, W, (short*)d_ws,
                                         (long)in_sizes[0], (long)in_sizes[1]);

    dim3 grid(N / 256, M / 256);           // 16x16 = 256 blocks = 1/CU
    gemm_pool_kernel<<<grid, 512, 0, stream>>>(xb, wb, b, out, K);
}